// Round 6
// baseline (243.380 us; speedup 1.0000x reference)
//
#include <hip/hip_runtime.h>

// Navier-Stokes physics-informed loss (f32 in, scalar f32 out).
// x,y: (64,3,512,512). Interior: b in [1,62], i in [1,510], j in [1,510].
// r0 = |dudx + dvdy|
// r1 = |dudt + u*dudx + v*dudy + dpdx - MU*lap(u)|
// r2 = |dvdt + u*dvdx + v*dvdy + dpdy - MU*lap(v)|
// dudt = (u[b+1]-u[b-1])*32 ; d/dx,d/dy central *127.5 ; MU/DX^2 = 0.65025
//
// Thread = (i-row, 4 consecutive j via float4); b register-marched.
// History: R2/R5: launch_bounds(256,4) forced VGPR=64 but true working set
// was 76 -> scratch spill (WRITE_SIZE 106-117MB), 206/224us. R3: (256,8) ->
// VGPR32, massive spill, 909us. R4: plain bounds, VGPR=76 no-spill BUT only
// 6 blocks/CU vs 2040-block grid -> tail, occ 29%, 165us.
// R6: cut TRUE pressure by ~12 regs (f32 chunk accumulators instead of 6
// doubles; drop w[4] mask array) so the (256,4) cap at 64 regs is honest:
// 8 blocks/CU = 2048 slots >= 2040 blocks, single round, zero spill.
// Verification metric: WRITE_SIZE must be ~0.2MB, not 100+MB.

constexpr int Wd   = 512;
constexpr int CSTR = 512 * 512;
constexpr int BSTR = 3 * 512 * 512;

__device__ __forceinline__ float4 ld4(const float* p) {
    return *reinterpret_cast<const float4*>(p);
}
__device__ __forceinline__ float4 scale4(float4 a, float s) {
    return make_float4(a.x * s, a.y * s, a.z * s, a.w * s);
}

__device__ __forceinline__ void step_tensor(
    const float* __restrict__ T, int c, int jt,
    float s, float sdx, float slap,
    float4& um, float4& uc, float4& vm, float4& vc,
    float r0[4], float r1[4], float r2[4])
{
    const float4 unr = ld4(T + c + BSTR);
    const float4 vnr = ld4(T + c + BSTR + CSTR);
    const float4 uxp = ld4(T + c + Wd);
    const float4 uxm = ld4(T + c - Wd);
    const float4 vxp = ld4(T + c + CSTR + Wd);
    const float4 vxm = ld4(T + c + CSTR - Wd);
    const float4 pxp = ld4(T + c + 2 * CSTR + Wd);
    const float4 pxm = ld4(T + c + 2 * CSTR - Wd);
    const float4 pcr = ld4(T + c + 2 * CSTR);

    const float un[4] = {unr.x * s, unr.y * s, unr.z * s, unr.w * s};
    const float vn[4] = {vnr.x * s, vnr.y * s, vnr.z * s, vnr.w * s};

    // j-neighbors: shuffle across lanes; wave-boundary lanes load the edge.
    float u_l = __shfl_up(uc.w, 1);
    float v_l = __shfl_up(vc.w, 1);
    float p_l = __shfl_up(pcr.w, 1);
    float u_r = __shfl_down(uc.x, 1);
    float v_r = __shfl_down(vc.x, 1);
    float p_r = __shfl_down(pcr.x, 1);
    if (jt == 64) {  // lane 0 of right half-row: needs j = 255
        u_l = T[c - 1] * s;
        v_l = T[c + CSTR - 1] * s;
        p_l = T[c + 2 * CSTR - 1];
    }
    if (jt == 63) {  // lane 63 of left half-row: needs j = 256
        u_r = T[c + 4] * s;
        v_r = T[c + CSTR + 4] * s;
        p_r = T[c + 2 * CSTR + 4];
    }

    const float ucA[4] = {uc.x, uc.y, uc.z, uc.w};
    const float vcA[4] = {vc.x, vc.y, vc.z, vc.w};
    const float umA[4] = {um.x, um.y, um.z, um.w};
    const float vmA[4] = {vm.x, vm.y, vm.z, vm.w};
    const float ul[4]  = {u_l, uc.x, uc.y, uc.z};
    const float ur4[4] = {uc.y, uc.z, uc.w, u_r};
    const float vl[4]  = {v_l, vc.x, vc.y, vc.z};
    const float vr4[4] = {vc.y, vc.z, vc.w, v_r};
    const float pl[4]  = {p_l, pcr.x, pcr.y, pcr.z};
    const float pr4[4] = {pcr.y, pcr.z, pcr.w, p_r};
    const float uxpA[4] = {uxp.x, uxp.y, uxp.z, uxp.w};
    const float uxmA[4] = {uxm.x, uxm.y, uxm.z, uxm.w};
    const float vxpA[4] = {vxp.x, vxp.y, vxp.z, vxp.w};
    const float vxmA[4] = {vxm.x, vxm.y, vxm.z, vxm.w};
    const float pxpA[4] = {pxp.x, pxp.y, pxp.z, pxp.w};
    const float pxmA[4] = {pxm.x, pxm.y, pxm.z, pxm.w};

    #pragma unroll
    for (int k = 0; k < 4; ++k) {
        const float dudx = (uxpA[k] - uxmA[k]) * sdx;
        const float dvdx = (vxpA[k] - vxmA[k]) * sdx;
        const float dpdx = (pxpA[k] - pxmA[k]) * sdx;
        const float dudy = (ur4[k] - ul[k]) * 127.5f;   // already scaled by s
        const float dvdy = (vr4[k] - vl[k]) * 127.5f;
        const float dpdy = (pr4[k] - pl[k]) * sdx;      // p raw
        const float lapu = (uxpA[k] + uxmA[k]) * slap
                         + (ur4[k] + ul[k]) * 0.65025f - 2.601f * ucA[k];
        const float lapv = (vxpA[k] + vxmA[k]) * slap
                         + (vl[k] + vr4[k]) * 0.65025f - 2.601f * vcA[k];
        r0[k] = fabsf(dudx + dvdy);
        r1[k] = fabsf((un[k] - umA[k]) * 32.0f + ucA[k] * dudx + vcA[k] * dudy
                      + dpdx - lapu);
        r2[k] = fabsf((vn[k] - vmA[k]) * 32.0f + ucA[k] * dvdx + vcA[k] * dvdy
                      + dpdy - lapv);
    }

    um = uc; uc = make_float4(un[0], un[1], un[2], un[3]);
    vm = vc; vc = make_float4(vn[0], vn[1], vn[2], vn[3]);
}

__global__ __launch_bounds__(256, 4)
void ns_loss_kernel(const float* __restrict__ X, const float* __restrict__ Y,
                    const float* __restrict__ stdp, double* __restrict__ acc)
{
    const float s    = *stdp;
    const float sdx  = s * 127.5f;
    const float slap = s * 0.65025f;

    // Bijective XCD-chunked swizzle. nwg = 2040 = 8*255, so each XCD owns
    // exactly one b-chunk (contiguous i-band -> i+-1 reuse within one L2).
    const int nwg  = gridDim.x;          // 2040
    const int q    = nwg >> 3;           // 255
    const int orig = blockIdx.x;
    const int xcd  = orig & 7;
    const int wg   = xcd * q + (orig >> 3);
    const int z = wg / 255;              // b-chunk 0..7
    const int y = wg % 255;              // i-pair 0..254

    const int tid = threadIdx.x;
    const int jt  = tid & 127;           // j-thread within row
    const int io  = tid >> 7;            // which of 2 rows
    const int i   = 1 + 2 * y + io;      // 1..510
    const int j0  = jt << 2;             // 0..508
    const int bs  = 1 + 8 * z;
    const int nsteps = min(8, 62 - 8 * z);   // 8,...,8,6

    int c = bs * BSTR + i * Wd + j0;

    float4 xum = scale4(ld4(X + c - BSTR), s);
    float4 xuc = scale4(ld4(X + c), s);
    float4 xvm = scale4(ld4(X + c - BSTR + CSTR), s);
    float4 xvc = scale4(ld4(X + c + CSTR), s);
    float4 yum = scale4(ld4(Y + c - BSTR), s);
    float4 yuc = scale4(ld4(Y + c), s);
    float4 yvm = scale4(ld4(Y + c - BSTR + CSTR), s);
    float4 yvc = scale4(ld4(Y + c + CSTR), s);

    // f32 chunk accumulators (saves 9 VGPRs vs 3 doubles; per-thread partial
    // <= ~5e6 over <=32 points -> rounding error negligible vs 3.1 threshold)
    float s0 = 0.0f, s1 = 0.0f, s2 = 0.0f;

    const bool edgeL = (j0 == 0);
    const bool edgeR = (j0 == 508);

    for (int it = 0; it < nsteps; ++it) {
        float r0x[4], r1x[4], r2x[4], r0y[4], r1y[4], r2y[4];
        step_tensor(X, c, jt, s, sdx, slap, xum, xuc, xvm, xvc, r0x, r1x, r2x);
        step_tensor(Y, c, jt, s, sdx, slap, yum, yuc, yvm, yvc, r0y, r1y, r2y);
        #pragma unroll
        for (int k = 0; k < 4; ++k) {
            float e0 = r0y[k] - r0x[k];
            float e1 = r1y[k] - r1x[k];
            float e2 = r2y[k] - r2x[k];
            if ((k == 0 && edgeL) || (k == 3 && edgeR)) {
                e0 = 0.0f; e1 = 0.0f; e2 = 0.0f;
            }
            s0 += e0 * e0;
            s1 += e1 * e1;
            s2 += e2 * e2;
        }
        c += BSTR;
    }

    // block reduction: f32 wave shuffle -> LDS -> f64 atomic per block
    for (int o = 32; o > 0; o >>= 1) {
        s0 += __shfl_down(s0, o);
        s1 += __shfl_down(s1, o);
        s2 += __shfl_down(s2, o);
    }
    __shared__ float sm[3][4];
    const int wid = threadIdx.x >> 6, lane = threadIdx.x & 63;
    if (lane == 0) { sm[0][wid] = s0; sm[1][wid] = s1; sm[2][wid] = s2; }
    __syncthreads();
    if (threadIdx.x == 0) {
        atomicAdd(&acc[0], (double)sm[0][0] + (double)sm[0][1]
                         + (double)sm[0][2] + (double)sm[0][3]);
        atomicAdd(&acc[1], (double)sm[1][0] + (double)sm[1][1]
                         + (double)sm[1][2] + (double)sm[1][3]);
        atomicAdd(&acc[2], (double)sm[2][0] + (double)sm[2][1]
                         + (double)sm[2][2] + (double)sm[2][3]);
    }
}

__global__ void ns_finalize_kernel(const double* __restrict__ acc,
                                   float* __restrict__ out)
{
    if (threadIdx.x == 0) {
        const double N = 62.0 * 510.0 * 510.0;
        out[0] = (float)(1.0e-3 * (acc[0] + acc[1] + acc[2]) / N);
    }
}

extern "C" void kernel_launch(void* const* d_in, const int* in_sizes, int n_in,
                              void* d_out, int out_size, void* d_ws, size_t ws_size,
                              hipStream_t stream) {
    const float* X    = (const float*)d_in[0];
    const float* Y    = (const float*)d_in[1];
    const float* stdp = (const float*)d_in[2];
    float* out  = (float*)d_out;
    double* acc = (double*)d_ws;

    hipMemsetAsync(acc, 0, 3 * sizeof(double), stream);

    dim3 block(256);
    dim3 grid(255 * 8);   // (i-pair) x (8 b-chunks), XCD-swizzled in-kernel
    ns_loss_kernel<<<grid, block, 0, stream>>>(X, Y, stdp, acc);
    ns_finalize_kernel<<<1, 64, 0, stream>>>(acc, out);
}

// Round 7
// 142.113 us; speedup vs baseline: 1.7126x; 1.7126x over previous
//
#include <hip/hip_runtime.h>

// Navier-Stokes physics-informed loss (f32 in, scalar f32 out).
// x,y: (64,3,512,512). Interior: b in [1,62], i in [1,510], j in [1,510].
// r0 = |dudx + dvdy|
// r1 = |dudt + u*dudx + v*dudy + dpdx - MU*lap(u)|
// r2 = |dvdt + u*dvdx + v*dvdy + dpdy - MU*lap(v)|
// dudt = (u[b+1]-u[b-1])*32 ; d/dx,d/dy central *127.5 ; MU/DX^2 = 0.65025
//
// Thread = (i-row, 4 consecutive j via float4); b register-marched.
// Register-pressure saga: honest working set = 76 VGPR (R4, no spill).
// Every attempt to cap below it (R3: 32, R5/R6: 64) spilled to scratch
// (WRITE_SIZE 100-270MB) and LOST. So: plain launch_bounds(256), VGPR=76,
// 6 blocks/CU -> capacity 1536 blocks. R4's failure was the 2040-block grid
// (full round + 504-block straggler tail -> time-avg occ 29%).
// R7: size grid TO capacity: 255 i-pairs x 6 b-chunks (11,11,11,11,11,7)
// = 1530 blocks <= 1536 slots -> all blocks resident, flat occupancy, no tail.

constexpr int Wd   = 512;
constexpr int CSTR = 512 * 512;
constexpr int BSTR = 3 * 512 * 512;

__device__ __forceinline__ float4 ld4(const float* p) {
    return *reinterpret_cast<const float4*>(p);
}
__device__ __forceinline__ float4 scale4(float4 a, float s) {
    return make_float4(a.x * s, a.y * s, a.z * s, a.w * s);
}

__device__ __forceinline__ void step_tensor(
    const float* __restrict__ T, int c, int jt,
    float s, float sdx, float slap,
    float4& um, float4& uc, float4& vm, float4& vc,
    float r0[4], float r1[4], float r2[4])
{
    const float4 unr = ld4(T + c + BSTR);
    const float4 vnr = ld4(T + c + BSTR + CSTR);
    const float4 uxp = ld4(T + c + Wd);
    const float4 uxm = ld4(T + c - Wd);
    const float4 vxp = ld4(T + c + CSTR + Wd);
    const float4 vxm = ld4(T + c + CSTR - Wd);
    const float4 pxp = ld4(T + c + 2 * CSTR + Wd);
    const float4 pxm = ld4(T + c + 2 * CSTR - Wd);
    const float4 pcr = ld4(T + c + 2 * CSTR);

    const float un[4] = {unr.x * s, unr.y * s, unr.z * s, unr.w * s};
    const float vn[4] = {vnr.x * s, vnr.y * s, vnr.z * s, vnr.w * s};

    // j-neighbors: shuffle across lanes; wave-boundary lanes load the edge.
    float u_l = __shfl_up(uc.w, 1);
    float v_l = __shfl_up(vc.w, 1);
    float p_l = __shfl_up(pcr.w, 1);
    float u_r = __shfl_down(uc.x, 1);
    float v_r = __shfl_down(vc.x, 1);
    float p_r = __shfl_down(pcr.x, 1);
    if (jt == 64) {  // lane 0 of right half-row: needs j = 255
        u_l = T[c - 1] * s;
        v_l = T[c + CSTR - 1] * s;
        p_l = T[c + 2 * CSTR - 1];
    }
    if (jt == 63) {  // lane 63 of left half-row: needs j = 256
        u_r = T[c + 4] * s;
        v_r = T[c + CSTR + 4] * s;
        p_r = T[c + 2 * CSTR + 4];
    }

    const float ucA[4] = {uc.x, uc.y, uc.z, uc.w};
    const float vcA[4] = {vc.x, vc.y, vc.z, vc.w};
    const float umA[4] = {um.x, um.y, um.z, um.w};
    const float vmA[4] = {vm.x, vm.y, vm.z, vm.w};
    const float ul[4]  = {u_l, uc.x, uc.y, uc.z};
    const float ur4[4] = {uc.y, uc.z, uc.w, u_r};
    const float vl[4]  = {v_l, vc.x, vc.y, vc.z};
    const float vr4[4] = {vc.y, vc.z, vc.w, v_r};
    const float pl[4]  = {p_l, pcr.x, pcr.y, pcr.z};
    const float pr4[4] = {pcr.y, pcr.z, pcr.w, p_r};
    const float uxpA[4] = {uxp.x, uxp.y, uxp.z, uxp.w};
    const float uxmA[4] = {uxm.x, uxm.y, uxm.z, uxm.w};
    const float vxpA[4] = {vxp.x, vxp.y, vxp.z, vxp.w};
    const float vxmA[4] = {vxm.x, vxm.y, vxm.z, vxm.w};
    const float pxpA[4] = {pxp.x, pxp.y, pxp.z, pxp.w};
    const float pxmA[4] = {pxm.x, pxm.y, pxm.z, pxm.w};

    #pragma unroll
    for (int k = 0; k < 4; ++k) {
        const float dudx = (uxpA[k] - uxmA[k]) * sdx;
        const float dvdx = (vxpA[k] - vxmA[k]) * sdx;
        const float dpdx = (pxpA[k] - pxmA[k]) * sdx;
        const float dudy = (ur4[k] - ul[k]) * 127.5f;   // already scaled by s
        const float dvdy = (vr4[k] - vl[k]) * 127.5f;
        const float dpdy = (pr4[k] - pl[k]) * sdx;      // p raw
        const float lapu = (uxpA[k] + uxmA[k]) * slap
                         + (ur4[k] + ul[k]) * 0.65025f - 2.601f * ucA[k];
        const float lapv = (vxpA[k] + vxmA[k]) * slap
                         + (vl[k] + vr4[k]) * 0.65025f - 2.601f * vcA[k];
        r0[k] = fabsf(dudx + dvdy);
        r1[k] = fabsf((un[k] - umA[k]) * 32.0f + ucA[k] * dudx + vcA[k] * dudy
                      + dpdx - lapu);
        r2[k] = fabsf((vn[k] - vmA[k]) * 32.0f + ucA[k] * dvdx + vcA[k] * dvdy
                      + dpdy - lapv);
    }

    um = uc; uc = make_float4(un[0], un[1], un[2], un[3]);
    vm = vc; vc = make_float4(vn[0], vn[1], vn[2], vn[3]);
}

__global__ __launch_bounds__(256)
void ns_loss_kernel(const float* __restrict__ X, const float* __restrict__ Y,
                    const float* __restrict__ stdp, double* __restrict__ acc)
{
    const float s    = *stdp;
    const float sdx  = s * 127.5f;
    const float slap = s * 0.65025f;

    // Bijective XCD-chunked swizzle (m204): nwg=1530, q=191, r=2.
    // Each XCD owns a contiguous band of (z-major, y-minor) ids -> adjacent
    // i rows within one b-chunk share that XCD's L2.
    const int nwg  = gridDim.x;          // 1530
    const int q    = nwg >> 3;           // 191
    const int r    = nwg & 7;            // 2
    const int orig = blockIdx.x;
    const int xcd  = orig & 7;
    const int wg   = (xcd < r ? xcd * (q + 1) : r * (q + 1) + (xcd - r) * q)
                   + (orig >> 3);
    const int z = wg / 255;              // b-chunk 0..5
    const int y = wg % 255;              // i-pair 0..254

    const int tid = threadIdx.x;
    const int jt  = tid & 127;           // j-thread within row
    const int io  = tid >> 7;            // which of 2 rows
    const int i   = 1 + 2 * y + io;      // 1..510
    const int j0  = jt << 2;             // 0..508
    const int bs  = 1 + 11 * z;
    const int nsteps = min(11, 62 - 11 * z);   // 11,11,11,11,11,7

    int c = bs * BSTR + i * Wd + j0;

    float4 xum = scale4(ld4(X + c - BSTR), s);
    float4 xuc = scale4(ld4(X + c), s);
    float4 xvm = scale4(ld4(X + c - BSTR + CSTR), s);
    float4 xvc = scale4(ld4(X + c + CSTR), s);
    float4 yum = scale4(ld4(Y + c - BSTR), s);
    float4 yuc = scale4(ld4(Y + c), s);
    float4 yvm = scale4(ld4(Y + c - BSTR + CSTR), s);
    float4 yvc = scale4(ld4(Y + c + CSTR), s);

    const float w[4] = {(j0 != 0) ? 1.0f : 0.0f, 1.0f, 1.0f,
                        (j0 != 508) ? 1.0f : 0.0f};

    double s0 = 0.0, s1 = 0.0, s2 = 0.0;

    for (int it = 0; it < nsteps; ++it) {
        float r0x[4], r1x[4], r2x[4], r0y[4], r1y[4], r2y[4];
        step_tensor(X, c, jt, s, sdx, slap, xum, xuc, xvm, xvc, r0x, r1x, r2x);
        step_tensor(Y, c, jt, s, sdx, slap, yum, yuc, yvm, yvc, r0y, r1y, r2y);
        #pragma unroll
        for (int k = 0; k < 4; ++k) {
            const float e0 = (r0y[k] - r0x[k]) * w[k];
            const float e1 = (r1y[k] - r1x[k]) * w[k];
            const float e2 = (r2y[k] - r2x[k]) * w[k];
            s0 += (double)e0 * (double)e0;
            s1 += (double)e1 * (double)e1;
            s2 += (double)e2 * (double)e2;
        }
        c += BSTR;
    }

    // block reduction: wave shuffle -> LDS -> one atomic per block
    for (int o = 32; o > 0; o >>= 1) {
        s0 += __shfl_down(s0, o);
        s1 += __shfl_down(s1, o);
        s2 += __shfl_down(s2, o);
    }
    __shared__ double sm[3][4];
    const int wid = threadIdx.x >> 6, lane = threadIdx.x & 63;
    if (lane == 0) { sm[0][wid] = s0; sm[1][wid] = s1; sm[2][wid] = s2; }
    __syncthreads();
    if (threadIdx.x == 0) {
        atomicAdd(&acc[0], sm[0][0] + sm[0][1] + sm[0][2] + sm[0][3]);
        atomicAdd(&acc[1], sm[1][0] + sm[1][1] + sm[1][2] + sm[1][3]);
        atomicAdd(&acc[2], sm[2][0] + sm[2][1] + sm[2][2] + sm[2][3]);
    }
}

__global__ void ns_finalize_kernel(const double* __restrict__ acc,
                                   float* __restrict__ out)
{
    if (threadIdx.x == 0) {
        const double N = 62.0 * 510.0 * 510.0;
        out[0] = (float)(1.0e-3 * (acc[0] + acc[1] + acc[2]) / N);
    }
}

extern "C" void kernel_launch(void* const* d_in, const int* in_sizes, int n_in,
                              void* d_out, int out_size, void* d_ws, size_t ws_size,
                              hipStream_t stream) {
    const float* X    = (const float*)d_in[0];
    const float* Y    = (const float*)d_in[1];
    const float* stdp = (const float*)d_in[2];
    float* out  = (float*)d_out;
    double* acc = (double*)d_ws;

    hipMemsetAsync(acc, 0, 3 * sizeof(double), stream);

    dim3 block(256);
    dim3 grid(255 * 6);   // 1530 blocks <= 6 blocks/CU * 256 CU capacity
    ns_loss_kernel<<<grid, block, 0, stream>>>(X, Y, stdp, acc);
    ns_finalize_kernel<<<1, 64, 0, stream>>>(acc, out);
}